// Round 1
// baseline (255.268 us; speedup 1.0000x reference)
//
#include <hip/hip_runtime.h>

#define B 8
#define N 2048
#define FIN 10
#define D 128
#define ALPHA 0.02f
#define BR 32     // rows per block, k_proj
#define TI 32     // rows per block, k_attn
#define JC 128    // j-chunk, k_attn
#define NBLK_ATTN ((N / TI) * B)   // 512

typedef short bf8 __attribute__((ext_vector_type(8)));   // 8 bf16 in 4 VGPRs
typedef short s4v __attribute__((ext_vector_type(4)));
typedef float f32x4 __attribute__((ext_vector_type(4)));

__device__ __forceinline__ float lrelu(float x) { return x >= 0.f ? x : ALPHA * x; }

__device__ __forceinline__ short f2b(float f) {
    unsigned u = __float_as_uint(f);
    return (short)((u + 0x7fffu + ((u >> 16) & 1u)) >> 16);
}

__device__ __forceinline__ float b2f(short s) {
    return __uint_as_float(((unsigned)(unsigned short)s) << 16);
}

__device__ __forceinline__ unsigned enc_key(float v) {
    unsigned b = __float_as_uint(v);
    return (b & 0x80000000u) ? ~b : (b | 0x80000000u);
}
__device__ __forceinline__ float dec_key(unsigned k) {
    unsigned b = (k & 0x80000000u) ? (k & 0x7fffffffu) : ~k;
    return __uint_as_float(b);
}

// ---------------------------------------------------------------------------
// k_proj: x = lrelu(LN(h@W1^T+b1)) [bf16] ; Wh = x@Wg^T+bg via MFMA (fp32 acc);
// emits WhT bf16 [d][j] + e1,e2 fp32. Also zero-inits pooled + completion cnt.
// Block = 32 rows, 256 threads (4 waves). Grid = B*N/32 = 512.  (unchanged)
// ---------------------------------------------------------------------------
__global__ __launch_bounds__(256) void k_proj(
    const float* __restrict__ h, const float* __restrict__ W1, const float* __restrict__ b1,
    const float* __restrict__ Wg, const float* __restrict__ bg,
    const float* __restrict__ a1, const float* __restrict__ a2,
    unsigned short* __restrict__ WhT, float* __restrict__ e1g, float* __restrict__ e2g,
    unsigned* __restrict__ pooled, unsigned* __restrict__ cnt)
{
    __shared__ __align__(16) short xep_lds[32 * 136];
    __shared__ __align__(16) short wg_lds[D * 136];
    __shared__ float W1_lds[D * 11];
    __shared__ float h_lds[BR * FIN];
    __shared__ float ep1[2][BR], ep2[2][BR];

    const int t = threadIdx.x;
    const int r0 = blockIdx.x * BR;
    const int bb = r0 >> 11;
    const int jloc = r0 & (N - 1);

    // zero-init pooled (blocks 0..7) and counter (block 0)
    if (blockIdx.x < B && t < D) pooled[blockIdx.x * D + t] = 0u;
    if (blockIdx.x == 0 && t == 128) *cnt = 0u;

    for (int idx = t; idx < D * FIN; idx += 256)
        W1_lds[(idx / FIN) * 11 + (idx % FIN)] = W1[idx];
    for (int idx = t; idx < BR * FIN; idx += 256)
        h_lds[idx] = h[(size_t)r0 * FIN + idx];
    __syncthreads();

    // stage Wg -> bf16 LDS [dout][din]
    {
        const int dr = t >> 4;
        const int j8 = t & 15;
        #pragma unroll
        for (int pass = 0; pass < 8; pass++) {
            int dd = pass * 16 + dr;
            float4 f0 = *(const float4*)&Wg[dd * D + j8 * 8];
            float4 f1 = *(const float4*)&Wg[dd * D + j8 * 8 + 4];
            bf8 v;
            v[0] = f2b(f0.x); v[1] = f2b(f0.y); v[2] = f2b(f0.z); v[3] = f2b(f0.w);
            v[4] = f2b(f1.x); v[5] = f2b(f1.y); v[6] = f2b(f1.z); v[7] = f2b(f1.w);
            *(bf8*)&wg_lds[dd * 136 + j8 * 8] = v;
        }
    }

    // phase 1: fc1 + LN + lrelu, one row per wave iteration
    const int w = t >> 6, lane = t & 63;
    {
        float b1v0 = b1[lane], b1v1 = b1[lane + 64];
        for (int i = 0; i < 8; i++) {
            int r = w * 8 + i;
            float s0 = b1v0, s1 = b1v1;
            const float* hr = &h_lds[r * FIN];
            #pragma unroll
            for (int k = 0; k < FIN; k++) {
                float hv = hr[k];
                s0 += hv * W1_lds[lane * 11 + k];
                s1 += hv * W1_lds[(lane + 64) * 11 + k];
            }
            float sm = s0 + s1, sq = s0 * s0 + s1 * s1;
            #pragma unroll
            for (int m = 1; m <= 32; m <<= 1) { sm += __shfl_xor(sm, m); sq += __shfl_xor(sq, m); }
            float mean = sm * (1.f / D);
            float var  = sq * (1.f / D) - mean * mean;
            float rs = rsqrtf(var + 1e-5f);
            xep_lds[r * 136 + lane]      = f2b(lrelu((s0 - mean) * rs));
            xep_lds[r * 136 + lane + 64] = f2b(lrelu((s1 - mean) * rs));
        }
    }
    __syncthreads();

    // phase 2: MFMA  Wh[32][128] = x @ Wg^T
    const int l15 = lane & 15, q = lane >> 4;
    const int mw = w & 1, np = w >> 1;
    f32x4 acc[4];
    #pragma unroll
    for (int nt = 0; nt < 4; nt++)
        #pragma unroll
        for (int r = 0; r < 4; r++) acc[nt][r] = 0.f;

    #pragma unroll
    for (int ks = 0; ks < 4; ks++) {
        bf8 av = *(const bf8*)&xep_lds[(mw * 16 + l15) * 136 + ks * 32 + q * 8];
        #pragma unroll
        for (int nt = 0; nt < 4; nt++) {
            bf8 bv = *(const bf8*)&wg_lds[((np * 4 + nt) * 16 + l15) * 136 + ks * 32 + q * 8];
            acc[nt] = __builtin_amdgcn_mfma_f32_16x16x32_bf16(av, bv, acc[nt], 0, 0, 0);
        }
    }

    // epilogue: +bg, e1/e2 partials
    float e1p[4] = {0.f, 0.f, 0.f, 0.f}, e2p[4] = {0.f, 0.f, 0.f, 0.f};
    #pragma unroll
    for (int nt = 0; nt < 4; nt++) {
        int col = (np * 4 + nt) * 16 + l15;
        float bgv = bg[col], a1v = a1[col], a2v = a2[col];
        #pragma unroll
        for (int r = 0; r < 4; r++) {
            float v = acc[nt][r] + bgv;
            acc[nt][r] = v;
            e1p[r] += v * a1v;
            e2p[r] += v * a2v;
        }
    }
    #pragma unroll
    for (int m = 1; m <= 8; m <<= 1) {
        #pragma unroll
        for (int r = 0; r < 4; r++) { e1p[r] += __shfl_xor(e1p[r], m); e2p[r] += __shfl_xor(e2p[r], m); }
    }
    if (l15 == 0) {
        #pragma unroll
        for (int r = 0; r < 4; r++) {
            ep1[np][mw * 16 + q * 4 + r] = e1p[r];
            ep2[np][mw * 16 + q * 4 + r] = e2p[r];
        }
    }
    __syncthreads();
    if (t < BR) {
        e1g[r0 + t] = ep1[0][t] + ep1[1][t];
        e2g[r0 + t] = ep2[0][t] + ep2[1][t];
    }
    #pragma unroll
    for (int nt = 0; nt < 4; nt++) {
        int col = (np * 4 + nt) * 16 + l15;
        #pragma unroll
        for (int r = 0; r < 4; r++)
            xep_lds[col * 36 + mw * 16 + q * 4 + r] = f2b(acc[nt][r]);
    }
    __syncthreads();
    {
        const int col = t >> 1, jh = (t & 1) * 16;
        unsigned short* dst = WhT + ((size_t)(bb * D + col)) * N + jloc + jh;
        #pragma unroll
        for (int i2 = 0; i2 < 4; i2++)
            *(uint2*)(dst + i2 * 4) = *(const uint2*)&xep_lds[col * 36 + jh + i2 * 4];
    }
}

// ---------------------------------------------------------------------------
// k_attn v2: flash-style GAT attention.
//  - B-fragments (WhT) loaded DIRECTLY from global (L2-resident) into regs,
//    issued before the barrier so L2 latency hides under the exp phase.
//    (removes 96 KB/chunk/block of LDS traffic)
//  - pT double-buffered -> ONE barrier per chunk (was two); exp phase of
//    chunk c+1 overlaps MFMA of chunk c across waves.
//  - row-sum l accumulated in f32 during phase A from the rounded bf16 P
//    (numerically identical to the old ones-MFMA), -25% MFMA count.
// Block = 32 i-rows, 512 threads (8 waves). Grid = (64, 8).
// ---------------------------------------------------------------------------
__global__ __launch_bounds__(512) void k_attn(
    const int* __restrict__ adj, const unsigned short* __restrict__ WhT,
    const float* __restrict__ e1g, const float* __restrict__ e2g,
    unsigned* __restrict__ pooled, unsigned* __restrict__ cnt,
    const float* __restrict__ W2, const float* __restrict__ b2,
    float* __restrict__ out)
{
    __shared__ __align__(16) short pT[2][TI * 136];  // A-op: [i][k=j], pad 8, dbuf
    __shared__ float statsp[4][TI][2];
    __shared__ float maxb[2][D];
    __shared__ float l_lds[TI];
    __shared__ int finalflag;

    const int t = threadIdx.x;
    const int b = blockIdx.y;
    const int i0 = blockIdx.x * TI;

    const int w = t >> 6, lane = t & 63;
    const int l15 = lane & 15, q = lane >> 4;
    const int mw = w & 1;          // m-tile (0/1)
    const int np = w >> 1;         // n-quarter (0..3), covers cols [np*32, np*32+32)

    // staging maps
    const int rg = t >> 5;                 // 0..15 -> rows {2rg, 2rg+1}
    const int jq = (t & 31) * 4;           // j offset within chunk (int4 granule)

    const float e1r0 = e1g[b * N + i0 + rg * 2];
    const float e1r1 = e1g[b * N + i0 + rg * 2 + 1];

    const unsigned short* WhTb = WhT + (size_t)b * D * N;
    const int* adjb = adj + ((size_t)b * N + i0) * N;
    // B-fragment row bases for this wave (fragment: row d, 8 consecutive k=j)
    const unsigned short* wrow0 = WhTb + (size_t)((np * 2 + 0) * 16 + l15) * N + q * 8;
    const unsigned short* wrow1 = WhTb + (size_t)((np * 2 + 1) * 16 + l15) * N + q * 8;

    f32x4 acc[2];
    #pragma unroll
    for (int nt = 0; nt < 2; nt++)
        #pragma unroll
        for (int r = 0; r < 4; r++) acc[nt][r] = 0.f;
    float ls0 = 0.f, ls1 = 0.f;

    // prefetch chunk 0 (adj + e2)
    int4 a0 = *(const int4*)(adjb + (size_t)(rg * 2) * N + jq);
    int4 a1r = *(const int4*)(adjb + (size_t)(rg * 2 + 1) * N + jq);
    float4 e2r = *(const float4*)&e2g[b * N + jq];

    for (int jc = 0; jc < N / JC; jc++) {
        // issue this chunk's B-fragment loads early (L2-hot; consumed after barrier)
        bf8 bv0[4], bv1[4];
        #pragma unroll
        for (int ks = 0; ks < 4; ks++) {
            bv0[ks] = *(const bf8*)(wrow0 + jc * JC + ks * 32);
            bv1[ks] = *(const bf8*)(wrow1 + jc * JC + ks * 32);
        }

        short* pTc = &pT[jc & 1][0];

        // phase A: exp + bf16 pack + f32 row-sum (of the rounded values)
        {
            s4v pv;
            pv[0] = f2b(a0.x ? __expf(lrelu(e1r0 + e2r.x)) : 0.f);
            pv[1] = f2b(a0.y ? __expf(lrelu(e1r0 + e2r.y)) : 0.f);
            pv[2] = f2b(a0.z ? __expf(lrelu(e1r0 + e2r.z)) : 0.f);
            pv[3] = f2b(a0.w ? __expf(lrelu(e1r0 + e2r.w)) : 0.f);
            ls0 += b2f(pv[0]) + b2f(pv[1]) + b2f(pv[2]) + b2f(pv[3]);
            *(s4v*)&pTc[(rg * 2) * 136 + jq] = pv;
            pv[0] = f2b(a1r.x ? __expf(lrelu(e1r1 + e2r.x)) : 0.f);
            pv[1] = f2b(a1r.y ? __expf(lrelu(e1r1 + e2r.y)) : 0.f);
            pv[2] = f2b(a1r.z ? __expf(lrelu(e1r1 + e2r.z)) : 0.f);
            pv[3] = f2b(a1r.w ? __expf(lrelu(e1r1 + e2r.w)) : 0.f);
            ls1 += b2f(pv[0]) + b2f(pv[1]) + b2f(pv[2]) + b2f(pv[3]);
            *(s4v*)&pTc[(rg * 2 + 1) * 136 + jq] = pv;
        }

        // prefetch next chunk's adj + e2 (hidden behind barrier + MFMA)
        if (jc < N / JC - 1) {
            const int j0n = (jc + 1) * JC;
            a0  = *(const int4*)(adjb + (size_t)(rg * 2) * N + j0n + jq);
            a1r = *(const int4*)(adjb + (size_t)(rg * 2 + 1) * N + j0n + jq);
            e2r = *(const float4*)&e2g[b * N + j0n + jq];
        }

        __syncthreads();   // pT[jc&1] visible; single barrier per chunk (dbuf)

        // MFMA: O[32][128] += P @ WhT^T   (A from LDS, B from global regs)
        #pragma unroll
        for (int ks = 0; ks < 4; ks++) {
            bf8 av = *(const bf8*)&pTc[(mw * 16 + l15) * 136 + ks * 32 + q * 8];
            acc[0] = __builtin_amdgcn_mfma_f32_16x16x32_bf16(av, bv0[ks], acc[0], 0, 0, 0);
            acc[1] = __builtin_amdgcn_mfma_f32_16x16x32_bf16(av, bv1[ks], acc[1], 0, 0, 0);
        }
        // no trailing barrier: next iteration writes the OTHER pT buffer
    }

    // row-sum reduce (32 threads share a row pair; xor<=16 stays in the half-wave)
    #pragma unroll
    for (int m = 1; m <= 16; m <<= 1) { ls0 += __shfl_xor(ls0, m); ls1 += __shfl_xor(ls1, m); }
    if ((t & 31) == 0) { l_lds[rg * 2] = ls0; l_lds[rg * 2 + 1] = ls1; }
    __syncthreads();

    // epilogue: /l -> LN stats (cross-np via LDS) -> lrelu -> max-pool
    float smr[4] = {0.f, 0.f, 0.f, 0.f}, sqr[4] = {0.f, 0.f, 0.f, 0.f};
    #pragma unroll
    for (int r = 0; r < 4; r++) {
        float rinv = 1.f / l_lds[mw * 16 + q * 4 + r];
        #pragma unroll
        for (int nt = 0; nt < 2; nt++) {
            float v = acc[nt][r] * rinv;
            acc[nt][r] = v;
            smr[r] += v;
            sqr[r] += v * v;
        }
    }
    #pragma unroll
    for (int m = 1; m <= 8; m <<= 1) {
        #pragma unroll
        for (int r = 0; r < 4; r++) { smr[r] += __shfl_xor(smr[r], m); sqr[r] += __shfl_xor(sqr[r], m); }
    }
    if (l15 == 0) {
        #pragma unroll
        for (int r = 0; r < 4; r++) {
            statsp[np][mw * 16 + q * 4 + r][0] = smr[r];
            statsp[np][mw * 16 + q * 4 + r][1] = sqr[r];
        }
    }
    __syncthreads();

    float mx[2] = {-1e30f, -1e30f};
    #pragma unroll
    for (int r = 0; r < 4; r++) {
        int row = mw * 16 + q * 4 + r;
        float s0 = statsp[0][row][0] + statsp[1][row][0] + statsp[2][row][0] + statsp[3][row][0];
        float s1 = statsp[0][row][1] + statsp[1][row][1] + statsp[2][row][1] + statsp[3][row][1];
        float mean = s0 * (1.f / D);
        float var  = s1 * (1.f / D) - mean * mean;
        float rs = rsqrtf(var + 1e-5f);
        #pragma unroll
        for (int nt = 0; nt < 2; nt++) {
            float v = lrelu((acc[nt][r] - mean) * rs);
            mx[nt] = fmaxf(mx[nt], v);
        }
    }
    #pragma unroll
    for (int m = 16; m <= 32; m <<= 1) {
        #pragma unroll
        for (int nt = 0; nt < 2; nt++) mx[nt] = fmaxf(mx[nt], __shfl_xor(mx[nt], m));
    }
    if (q == 0) {
        #pragma unroll
        for (int nt = 0; nt < 2; nt++) maxb[mw][(np * 2 + nt) * 16 + l15] = mx[nt];
    }
    __syncthreads();
    if (t < D) {
        float v = fmaxf(maxb[0][t], maxb[1][t]);
        atomicMax(&pooled[b * D + t], enc_key(v));
    }
    __syncthreads();           // all this block's atomics drained

    // completion counter; last block does final 128->2 matmul + log_softmax
    if (t == 0) {
        __threadfence();
        unsigned old = atomicAdd(cnt, 1u);
        finalflag = (old == NBLK_ATTN - 1) ? 1 : 0;
    }
    __syncthreads();
    if (finalflag && t < 256) {
        const int fb = t >> 5;
        const int fq = t & 31;
        float s0 = 0.f, s1 = 0.f;
        #pragma unroll
        for (int m = 0; m < 4; m++) {
            int dd = fq + 32 * m;
            unsigned key = __hip_atomic_load(&pooled[fb * D + dd], __ATOMIC_RELAXED,
                                             __HIP_MEMORY_SCOPE_AGENT);
            float v = dec_key(key);
            s0 += v * W2[dd];
            s1 += v * W2[D + dd];
        }
        #pragma unroll
        for (int m = 1; m <= 16; m <<= 1) { s0 += __shfl_xor(s0, m); s1 += __shfl_xor(s1, m); }
        if (fq == 0) {
            float o0 = s0 + b2[0], o1 = s1 + b2[1];
            float mxv = fmaxf(o0, o1);
            float ls = logf(__expf(o0 - mxv) + __expf(o1 - mxv));
            out[fb * 2 + 0] = o0 - mxv - ls;
            out[fb * 2 + 1] = o1 - mxv - ls;
        }
    }
}

extern "C" void kernel_launch(void* const* d_in, const int* in_sizes, int n_in,
                              void* d_out, int out_size, void* d_ws, size_t ws_size,
                              hipStream_t stream) {
    const float* h   = (const float*)d_in[0];
    const int*   adj = (const int*)d_in[1];
    const float* W1  = (const float*)d_in[2];
    const float* b1  = (const float*)d_in[3];
    const float* Wg  = (const float*)d_in[4];
    const float* bg  = (const float*)d_in[5];
    const float* a1  = (const float*)d_in[6];
    const float* a2  = (const float*)d_in[7];
    const float* W2  = (const float*)d_in[8];
    const float* b2  = (const float*)d_in[9];
    float* out = (float*)d_out;

    unsigned short* WhT = (unsigned short*)d_ws;                       // B*D*N bf16
    float* e1g = (float*)((char*)d_ws + (size_t)B * D * N * 2);        // B*N f32
    float* e2g = e1g + (size_t)B * N;                                  // B*N f32
    unsigned* pooled = (unsigned*)(e2g + (size_t)B * N);               // B*D u32
    unsigned* cnt = pooled + (size_t)B * D;                            // 1 u32

    k_proj<<<(B * N) / BR, 256, 0, stream>>>(h, W1, b1, Wg, bg, a1, a2,
                                             WhT, e1g, e2g, pooled, cnt);
    k_attn<<<dim3(N / TI, B), 512, 0, stream>>>(adj, WhT, e1g, e2g, pooled, cnt,
                                                W2, b2, out);
}